// Round 8
// baseline (22719.437 us; speedup 1.0000x reference)
//
#include <hip/hip_runtime.h>
#include <hip/hip_bf16.h>
#include <cstddef>
#include <type_traits>

typedef unsigned int u32;
typedef short bf16x8 __attribute__((ext_vector_type(8)));
typedef float f32x4 __attribute__((ext_vector_type(4)));
typedef _Float16 hf2 __attribute__((ext_vector_type(2)));

#define TC 256          // time-chunk length
#define NCHUNK 8        // 2048 / TC

// ---------- helpers ----------
__device__ __forceinline__ float sigf(float x) {
    return __builtin_amdgcn_rcpf(1.f + __expf(-x));
}
__device__ __forceinline__ float tanhf_fast(float x) {
    return 1.f - 2.f * __builtin_amdgcn_rcpf(1.f + __expf(2.f * x));
}
// fp16-pair dot with f32 accumulate: v_dot2_f32_f16 when available
__device__ __forceinline__ float dotp(u32 w, u32 h, float acc) {
#if __has_builtin(__builtin_amdgcn_fdot2)
    return __builtin_amdgcn_fdot2(__builtin_bit_cast(hf2, w),
                                  __builtin_bit_cast(hf2, h), acc, false);
#else
    hf2 wv = __builtin_bit_cast(hf2, w);
    hf2 hv = __builtin_bit_cast(hf2, h);
    return fmaf((float)wv.y, (float)hv.y, fmaf((float)wv.x, (float)hv.x, acc));
#endif
}
__device__ __forceinline__ float dot4(uint4 w, uint4 h, float acc) {
    acc = dotp(w.x, h.x, acc);
    acc = dotp(w.y, h.y, acc);
    acc = dotp(w.z, h.z, acc);
    acc = dotp(w.w, h.w, acc);
    return acc;
}

// ---------- dtype sniff: is this buffer bf16 (1) or fp32 (0)? ----------
__global__ void sniff(const u32* __restrict__ src, int nwords, int* __restrict__ flag) {
    __shared__ int cnt[256];
    int tid = threadIdx.x;
    size_t idx = (size_t)tid * (size_t)nwords / 256;
    u32 u = src[idx];
    int e = (u >> 7) & 0xFF;
    cnt[tid] = (e >= 100 && e <= 140) ? 1 : 0;
    __syncthreads();
    for (int s = 128; s > 0; s >>= 1) {
        if (tid < s) cnt[tid] += cnt[tid + s];
        __syncthreads();
    }
    if (tid == 0) *flag = (cnt[0] >= 144) ? 1 : 0;
}

// ---------- generic convert (bf16-or-f32 source) -> bf16 ----------
__global__ void conv_any(const void* __restrict__ src, __hip_bfloat16* __restrict__ dst,
                         int n, const int* __restrict__ flag) {
    int i = blockIdx.x * 256 + threadIdx.x;
    if (i >= n) return;
    if (*flag)
        dst[i] = ((const __hip_bfloat16*)src)[i];
    else
        dst[i] = __float2bfloat16(((const float*)src)[i]);
}

// ---------- per-chunk X convert: X[b][tc*256+ti][128] -> Xc_b[b][ti][128] ----------
__global__ void conv_x(const void* __restrict__ X, __hip_bfloat16* __restrict__ dst,
                       int tc, const int* __restrict__ flag) {
    int i = blockIdx.x * 256 + threadIdx.x;     // 2097152 total
    int b = i >> 15, rem = i & 32767, ti = rem >> 7, d = rem & 127;
    size_t s = ((size_t)(b * 2048 + tc * TC + ti) << 7) | d;
    float v = (*flag) ? __bfloat162float(((const __hip_bfloat16*)X)[s])
                      : ((const float*)X)[s];
    dst[i] = __float2bfloat16(v);
}

// ---------- pack Wh [256][1024] -> quad-major fp16-pair uint4 [32][1024] ----------
__global__ void pack_whq(const void* __restrict__ Wh, uint4* __restrict__ Whq,
                         const int* __restrict__ flag) {
    int i = blockIdx.x * 256 + threadIdx.x;   // 32768 total
    int q = i >> 10, n = i & 1023;
    float w[8];
    if (*flag) {
        const __hip_bfloat16* p = (const __hip_bfloat16*)Wh;
#pragma unroll
        for (int j = 0; j < 8; ++j) w[j] = __bfloat162float(p[(8 * q + j) * 1024 + n]);
    } else {
        const float* p = (const float*)Wh;
#pragma unroll
        for (int j = 0; j < 8; ++j) w[j] = p[(8 * q + j) * 1024 + n];
    }
    u32 r[4];
#pragma unroll
    for (int pp = 0; pp < 4; ++pp) {
        hf2 hp; hp.x = (_Float16)w[2 * pp]; hp.y = (_Float16)w[2 * pp + 1];
        r[pp] = __builtin_bit_cast(u32, hp);
    }
    Whq[i] = make_uint4(r[0], r[1], r[2], r[3]);
}

// ---------- init per-run sync state: hx slot0 = 0, flags = 0 ----------
__global__ void init_sync(u32* __restrict__ hx, int* __restrict__ sflag) {
    int i = blockIdx.x * 256 + threadIdx.x;   // 8192 total
    if (i < 64 * 128) {                       // hx[b][slot0][w]
        int b = i >> 7, w = i & 127;
        hx[b * 256 + w] = 0;
    }
    if (i < 256) sflag[i] = 0;
}

// ---------- GEMM: C[row(m)][N] = A[m][K](bf16) @ B[K][N](bf16) + bias ----------
template <typename OutT>
__global__ void gemm_bias(const __hip_bfloat16* __restrict__ A,
                          const __hip_bfloat16* __restrict__ B,
                          const __hip_bfloat16* __restrict__ bias,
                          OutT* __restrict__ C, int N, int K,
                          long strideA, long strideC) {
    __shared__ short As[64 * 72];
    __shared__ short Bs[64 * 72];
    const int tid = threadIdx.x;
    const int n0 = blockIdx.x * 64;
    const int m0 = blockIdx.y * 64;
    const int w = tid >> 6, lane = tid & 63;
    const int lm = lane & 15, lq = lane >> 4;

    f32x4 acc[4];
#pragma unroll
    for (int i = 0; i < 4; ++i) acc[i] = (f32x4){0.f, 0.f, 0.f, 0.f};

    const int kchunks = K >> 6;
    for (int kc = 0; kc < kchunks; ++kc) {
#pragma unroll
        for (int p = 0; p < 2; ++p) {
            int m = m0 + (tid >> 3) + 32 * p;
            int ch = tid & 7;
            size_t aoff = ((size_t)(m >> 8) * strideA + (m & 255)) * K;
            uint4 v = *(const uint4*)(A + aoff + kc * 64 + ch * 8);
            *(uint4*)(As + ((tid >> 3) + 32 * p) * 72 + ch * 8) = v;
        }
#pragma unroll
        for (int p = 0; p < 2; ++p) {
            int k  = (tid >> 3) + 32 * p;
            int ne = (tid & 7) * 8;
            uint4 v = *(const uint4*)(B + (size_t)(kc * 64 + k) * N + n0 + ne);
            const short* sv = (const short*)&v;
#pragma unroll
            for (int e = 0; e < 8; ++e) Bs[(ne + e) * 72 + k] = sv[e];
        }
        __syncthreads();
#pragma unroll
        for (int ks = 0; ks < 2; ++ks) {
            bf16x8 af = *(const bf16x8*)(As + (16 * w + lm) * 72 + ks * 32 + lq * 8);
#pragma unroll
            for (int nt = 0; nt < 4; ++nt) {
                bf16x8 bfr = *(const bf16x8*)(Bs + (nt * 16 + lm) * 72 + ks * 32 + lq * 8);
                acc[nt] = __builtin_amdgcn_mfma_f32_16x16x32_bf16(af, bfr, acc[nt], 0, 0, 0);
            }
        }
        __syncthreads();
    }
#pragma unroll
    for (int nt = 0; nt < 4; ++nt) {
        int col = n0 + nt * 16 + lm;
        float bv = __bfloat162float(bias[col]);
#pragma unroll
        for (int r = 0; r < 4; ++r) {
            int mrow = m0 + 16 * w + lq * 4 + r;
            size_t coff = ((size_t)(mrow >> 8) * strideC + (mrow & 255)) * N;
            float v = acc[nt][r] + bv;
            if constexpr (std::is_same_v<OutT, _Float16>)
                C[coff + col] = (_Float16)v;
            else if constexpr (std::is_same_v<OutT, float>)
                C[coff + col] = v;
            else
                C[coff + col] = __float2bfloat16(v);
        }
    }
}

// ---------- LSTM recurrence: 4 WGs (256 thr) per batch, 256 WGs = 256 CUs ----------
// bid = p*64 + b: batch b (0..63), part p (0..3). Partners {b,b+64,b+128,b+192}
// land on the SAME XCD (64 % 8 == 0) -> exchange stays in local L2.
// WG owns h-cols [p*64, p*64+64) for all 4 gates = 256 gate-cols.
// Thread: gate g = tid>>6, j = tid&63, col = g*256 + p*64 + j.
// All 32 weight quads resident: LDSQ=20 in LDS (80 KB -> 1 WG/CU), REGQ=12 in
// VGPRs (48 regs; 256-thr blocks compile clean per r3 -- no 128-reg wall).
// Per-step h exchange: version V = tc*256+t. Read hx[b][V&1] (flags>=V),
// publish h_{V+1} into hx[b][(V+1)&1], flag[b][p]=V+1. Agent-scope atomics.
// 2-slot WAR-safe: publishing V+1 requires all partners at >=V, i.e. done
// reading V-1 (same slot). Residency guaranteed by cooperative launch.
#define LDSQ 20
#define REGQ 12

__global__ __launch_bounds__(256) void lstm_rec_chunk(
        const _Float16* __restrict__ xg_c,    // [64][TC][1024]
        const uint4* __restrict__ Whq,        // [32][1024] fp16-pair quads
        __hip_bfloat16* __restrict__ hs_c,    // [64][TC][256]
        float* __restrict__ cstate,           // [64][256]
        u32* __restrict__ hx,                 // [64][2][128] fp16-pair h versions
        int* __restrict__ sflag,              // [64][4] published version
        int first, int tc) {
    const int tid = threadIdx.x;              // 0..255
    const int b = blockIdx.x & 63;
    const int p = blockIdx.x >> 6;
    const int g = tid >> 6, j = tid & 63;
    const int col = g * 256 + p * 64 + j;

    __shared__ uint4 wlds[LDSQ * 256];        // 80 KB -> forces 1 WG/CU
    __shared__ float garr[256];
    __shared__ alignas(16) u32 hpair[128];

    // stage LDS weight quads (coalesced: consecutive j -> consecutive cols)
#pragma unroll
    for (int q = 0; q < LDSQ; ++q)
        wlds[q * 256 + tid] = Whq[q * 1024 + col];
    // register-resident quads (static indices only)
    uint4 wr[REGQ];
#pragma unroll
    for (int r = 0; r < REGQ; ++r)
        wr[r] = Whq[(LDSQ + r) * 1024 + col];

    float c = 0.f;
    if (tid < 64)
        c = first ? 0.f : cstate[b * 256 + p * 64 + tid];

    u32* hxb = hx + b * 256;                  // [2][128]
    int* fb = sflag + b * 4;
    const _Float16* xgp = xg_c + (size_t)b * TC * 1024 + col;
    __hip_bfloat16* hsp = hs_c + (size_t)b * TC * 256 + p * 64 + tid;  // tid<64
    const uint4* hq4 = (const uint4*)hpair;

    int V = tc * TC;                          // h version consumed at step t
    for (int t = 0; t < TC; ++t, ++V) {
        // xg load issued early (independent of exchange)
        float x = (float)xgp[(size_t)t * 1024];

        // 1) wait until all 4 parts published version V
        if (tid == 0) {
#pragma unroll
            for (int k = 0; k < 4; ++k)
                while (__hip_atomic_load(&fb[k], __ATOMIC_ACQUIRE,
                                         __HIP_MEMORY_SCOPE_AGENT) < V)
                    __builtin_amdgcn_s_sleep(1);
        }
        __syncthreads();
        // 2) gather h(V) into LDS
        if (tid < 128)
            hpair[tid] = __hip_atomic_load(&hxb[(V & 1) * 128 + tid],
                                           __ATOMIC_RELAXED, __HIP_MEMORY_SCOPE_AGENT);
        __syncthreads();

        // 3) dot over 32 quads (20 LDS + 12 reg), 4 cycling accumulators
        float a0 = 0.f, a1 = 0.f, a2 = 0.f, a3 = 0.f;
#pragma unroll
        for (int q = 0; q < LDSQ; ++q) {
            uint4 hv = hq4[q];                // uniform-address broadcast b128
            uint4 w = wlds[q * 256 + tid];
            if ((q & 3) == 0) a0 = dot4(w, hv, a0);
            else if ((q & 3) == 1) a1 = dot4(w, hv, a1);
            else if ((q & 3) == 2) a2 = dot4(w, hv, a2);
            else a3 = dot4(w, hv, a3);
        }
#pragma unroll
        for (int r = 0; r < REGQ; ++r) {
            int q = LDSQ + r;
            uint4 hv = hq4[q];
            if ((q & 3) == 0) a0 = dot4(wr[r], hv, a0);
            else if ((q & 3) == 1) a1 = dot4(wr[r], hv, a1);
            else if ((q & 3) == 2) a2 = dot4(wr[r], hv, a2);
            else a3 = dot4(wr[r], hv, a3);
        }
        float gsum = x + (a0 + a1) + (a2 + a3);

        // 4) activation + gate exchange (within WG)
        float s = (tid < 192) ? sigf(gsum) : tanhf_fast(gsum);  // f,i,o sig; c tanh
        garr[tid] = s;
        __syncthreads();
        // 5) owner threads update c,h; publish h(V+1)
        if (tid < 64) {
            float f  = garr[tid];
            float ig = garr[64 + tid];
            float og = garr[128 + tid];
            float ct = garr[192 + tid];
            c = c * f + ct * ig;
            float h = og * tanhf_fast(c);
            hsp[(size_t)t * 256] = __float2bfloat16(h);
            float hp = __shfl_xor(h, 1);
            if (!(tid & 1)) {
                hf2 pk; pk.x = (_Float16)h; pk.y = (_Float16)hp;
                __hip_atomic_store(&hxb[((V + 1) & 1) * 128 + p * 32 + (tid >> 1)],
                                   __builtin_bit_cast(u32, pk),
                                   __ATOMIC_RELAXED, __HIP_MEMORY_SCOPE_AGENT);
            }
        }
        __syncthreads();   // barrier drains vmcnt -> publishes at coherence point
        if (tid == 0)
            __hip_atomic_store(&fb[p], V + 1, __ATOMIC_RELEASE,
                               __HIP_MEMORY_SCOPE_AGENT);
    }
    if (tid < 64)
        cstate[b * 256 + p * 64 + tid] = c;
}

// ---------- launch ----------
extern "C" void kernel_launch(void* const* d_in, const int* in_sizes, int n_in,
                              void* d_out, int out_size, void* d_ws, size_t ws_size,
                              hipStream_t stream) {
    const void* X    = d_in[0];  // [64,2048,128] fp32 (sniffed)
    const void* Wx   = d_in[1];  // [128,1024]
    const void* Wh   = d_in[2];  // [256,1024]
    const void* bg   = d_in[3];  // [1024]
    const void* Wout = d_in[4];  // [256,128]
    const void* bout = d_in[5];  // [128]
    float* out = (float*)d_out;  // [64,2048,128] fp32 (reference output dtype)

    // workspace layout (~47.2 MB)
    char* ws = (char*)d_ws;
    _Float16* xg_c        = (_Float16*)(ws + 0);                 // 33554432
    __hip_bfloat16* Xc_b  = (__hip_bfloat16*)(ws + 33554432);    //  4194304
    __hip_bfloat16* hs_c  = (__hip_bfloat16*)(ws + 37748736);    //  8388608
    uint4* Whq            = (uint4*)(ws + 46137344);             //   524288
    __hip_bfloat16* Wxb   = (__hip_bfloat16*)(ws + 46661632);    //   262144
    __hip_bfloat16* Woutb = (__hip_bfloat16*)(ws + 46923776);    //    65536
    __hip_bfloat16* bgb   = (__hip_bfloat16*)(ws + 46989312);    //     2048
    __hip_bfloat16* boutb = (__hip_bfloat16*)(ws + 46991360);    //      512
    u32* hx               = (u32*)(ws + 46991872);               //    65536
    float* cstate         = (float*)(ws + 47057408);             //    65536
    int* flags            = (int*)(ws + 47122944);               //       64
    int* sflag            = (int*)(ws + 47123008);               //     1024

    // 1) per-tensor dtype sniff
    for (int i = 0; i < 6; ++i)
        sniff<<<dim3(1), dim3(256), 0, stream>>>((const u32*)d_in[i],
                                                 in_sizes[i] / 2, flags + i);
    // 2) canonicalize weights/biases; Wh to quad-major fp16 pairs; sync init
    conv_any<<<dim3(512), dim3(256), 0, stream>>>(Wx, Wxb, 131072, flags + 1);
    conv_any<<<dim3(128), dim3(256), 0, stream>>>(Wout, Woutb, 32768, flags + 4);
    conv_any<<<dim3(4),   dim3(256), 0, stream>>>(bg, bgb, 1024, flags + 3);
    conv_any<<<dim3(1),   dim3(256), 0, stream>>>(bout, boutb, 128, flags + 5);
    pack_whq<<<dim3(128), dim3(256), 0, stream>>>(Wh, Whq, flags + 2);
    init_sync<<<dim3(32), dim3(256), 0, stream>>>(hx, sflag);

    for (int tc = 0; tc < NCHUNK; ++tc) {
        // 3) X chunk -> bf16 [64][256][128]
        conv_x<<<dim3(8192), dim3(256), 0, stream>>>(X, Xc_b, tc, flags + 0);
        // 4) xg_c = Xc_b @ Wxb + bgb : M=16384, N=1024, K=128
        gemm_bias<_Float16><<<dim3(16, 256), dim3(256), 0, stream>>>(
            Xc_b, Wxb, bgb, xg_c, 1024, 128, 256L, 256L);
        // 5) recurrence: cooperative launch guarantees all 256 WGs co-resident
        {
            int first = (tc == 0) ? 1 : 0;
            int tcv = tc;
            const _Float16* xg_a = xg_c;
            const uint4* wh_a = Whq;
            __hip_bfloat16* hs_a = hs_c;
            float* cs_a = cstate;
            u32* hx_a = hx;
            int* sf_a = sflag;
            void* args[] = {(void*)&xg_a, (void*)&wh_a, (void*)&hs_a,
                            (void*)&cs_a, (void*)&hx_a, (void*)&sf_a,
                            (void*)&first, (void*)&tcv};
            hipLaunchCooperativeKernel((const void*)lstm_rec_chunk,
                                       dim3(256), dim3(256), args, 0, stream);
        }
        // 6) outc = hs_c @ Woutb + boutb : M=16384, N=128, K=256  (fp32 out)
        float* outc = out + (size_t)tc * TC * 128;
        gemm_bias<float><<<dim3(2, 256), dim3(256), 0, stream>>>(
            hs_c, Woutb, boutb, outc, 128, 256, 256L, 2048L);
    }
}

// Round 9
// 6832.832 us; speedup vs baseline: 3.3250x; 3.3250x over previous
//
#include <hip/hip_runtime.h>
#include <hip/hip_bf16.h>
#include <cstddef>
#include <type_traits>

typedef unsigned int u32;
typedef short bf16x8 __attribute__((ext_vector_type(8)));
typedef float f32x4 __attribute__((ext_vector_type(4)));
typedef _Float16 hf2 __attribute__((ext_vector_type(2)));

#define TC 256          // time-chunk length
#define NCHUNK 8        // 2048 / TC

// ---------- helpers ----------
__device__ __forceinline__ float sigf(float x) {
    return __builtin_amdgcn_rcpf(1.f + __expf(-x));
}
__device__ __forceinline__ float tanhf_fast(float x) {
    return 1.f - 2.f * __builtin_amdgcn_rcpf(1.f + __expf(2.f * x));
}
// fp16-pair dot with f32 accumulate: v_dot2_f32_f16 when available
__device__ __forceinline__ float dotp(u32 w, u32 h, float acc) {
#if __has_builtin(__builtin_amdgcn_fdot2)
    return __builtin_amdgcn_fdot2(__builtin_bit_cast(hf2, w),
                                  __builtin_bit_cast(hf2, h), acc, false);
#else
    hf2 wv = __builtin_bit_cast(hf2, w);
    hf2 hv = __builtin_bit_cast(hf2, h);
    return fmaf((float)wv.y, (float)hv.y, fmaf((float)wv.x, (float)hv.x, acc));
#endif
}
__device__ __forceinline__ float dot4(uint4 w, uint4 h, float acc) {
    acc = dotp(w.x, h.x, acc);
    acc = dotp(w.y, h.y, acc);
    acc = dotp(w.z, h.z, acc);
    acc = dotp(w.w, h.w, acc);
    return acc;
}

// ---------- dtype sniff: is this buffer bf16 (1) or fp32 (0)? ----------
__global__ void sniff(const u32* __restrict__ src, int nwords, int* __restrict__ flag) {
    __shared__ int cnt[256];
    int tid = threadIdx.x;
    size_t idx = (size_t)tid * (size_t)nwords / 256;
    u32 u = src[idx];
    int e = (u >> 7) & 0xFF;
    cnt[tid] = (e >= 100 && e <= 140) ? 1 : 0;
    __syncthreads();
    for (int s = 128; s > 0; s >>= 1) {
        if (tid < s) cnt[tid] += cnt[tid + s];
        __syncthreads();
    }
    if (tid == 0) *flag = (cnt[0] >= 144) ? 1 : 0;
}

// ---------- generic convert (bf16-or-f32 source) -> bf16 ----------
__global__ void conv_any(const void* __restrict__ src, __hip_bfloat16* __restrict__ dst,
                         int n, const int* __restrict__ flag) {
    int i = blockIdx.x * 256 + threadIdx.x;
    if (i >= n) return;
    if (*flag)
        dst[i] = ((const __hip_bfloat16*)src)[i];
    else
        dst[i] = __float2bfloat16(((const float*)src)[i]);
}

// ---------- per-chunk X convert: X[b][tc*256+ti][128] -> Xc_b[b][ti][128] ----------
__global__ void conv_x(const void* __restrict__ X, __hip_bfloat16* __restrict__ dst,
                       int tc, const int* __restrict__ flag) {
    int i = blockIdx.x * 256 + threadIdx.x;     // 2097152 total
    int b = i >> 15, rem = i & 32767, ti = rem >> 7, d = rem & 127;
    size_t s = ((size_t)(b * 2048 + tc * TC + ti) << 7) | d;
    float v = (*flag) ? __bfloat162float(((const __hip_bfloat16*)X)[s])
                      : ((const float*)X)[s];
    dst[i] = __float2bfloat16(v);
}

// ---------- pack Wh [256][1024] -> quad-major fp16-pair uint4 [32][1024] ----------
__global__ void pack_whq(const void* __restrict__ Wh, uint4* __restrict__ Whq,
                         const int* __restrict__ flag) {
    int i = blockIdx.x * 256 + threadIdx.x;   // 32768 total
    int q = i >> 10, n = i & 1023;
    float w[8];
    if (*flag) {
        const __hip_bfloat16* p = (const __hip_bfloat16*)Wh;
#pragma unroll
        for (int j = 0; j < 8; ++j) w[j] = __bfloat162float(p[(8 * q + j) * 1024 + n]);
    } else {
        const float* p = (const float*)Wh;
#pragma unroll
        for (int j = 0; j < 8; ++j) w[j] = p[(8 * q + j) * 1024 + n];
    }
    u32 r[4];
#pragma unroll
    for (int pp = 0; pp < 4; ++pp) {
        hf2 hp; hp.x = (_Float16)w[2 * pp]; hp.y = (_Float16)w[2 * pp + 1];
        r[pp] = __builtin_bit_cast(u32, hp);
    }
    Whq[i] = make_uint4(r[0], r[1], r[2], r[3]);
}

// ---------- GEMM: C[row(m)][N] = A[m][K](bf16) @ B[K][N](bf16) + bias ----------
template <typename OutT>
__global__ void gemm_bias(const __hip_bfloat16* __restrict__ A,
                          const __hip_bfloat16* __restrict__ B,
                          const __hip_bfloat16* __restrict__ bias,
                          OutT* __restrict__ C, int N, int K,
                          long strideA, long strideC) {
    __shared__ short As[64 * 72];
    __shared__ short Bs[64 * 72];
    const int tid = threadIdx.x;
    const int n0 = blockIdx.x * 64;
    const int m0 = blockIdx.y * 64;
    const int w = tid >> 6, lane = tid & 63;
    const int lm = lane & 15, lq = lane >> 4;

    f32x4 acc[4];
#pragma unroll
    for (int i = 0; i < 4; ++i) acc[i] = (f32x4){0.f, 0.f, 0.f, 0.f};

    const int kchunks = K >> 6;
    for (int kc = 0; kc < kchunks; ++kc) {
#pragma unroll
        for (int p = 0; p < 2; ++p) {
            int m = m0 + (tid >> 3) + 32 * p;
            int ch = tid & 7;
            size_t aoff = ((size_t)(m >> 8) * strideA + (m & 255)) * K;
            uint4 v = *(const uint4*)(A + aoff + kc * 64 + ch * 8);
            *(uint4*)(As + ((tid >> 3) + 32 * p) * 72 + ch * 8) = v;
        }
#pragma unroll
        for (int p = 0; p < 2; ++p) {
            int k  = (tid >> 3) + 32 * p;
            int ne = (tid & 7) * 8;
            uint4 v = *(const uint4*)(B + (size_t)(kc * 64 + k) * N + n0 + ne);
            const short* sv = (const short*)&v;
#pragma unroll
            for (int e = 0; e < 8; ++e) Bs[(ne + e) * 72 + k] = sv[e];
        }
        __syncthreads();
#pragma unroll
        for (int ks = 0; ks < 2; ++ks) {
            bf16x8 af = *(const bf16x8*)(As + (16 * w + lm) * 72 + ks * 32 + lq * 8);
#pragma unroll
            for (int nt = 0; nt < 4; ++nt) {
                bf16x8 bfr = *(const bf16x8*)(Bs + (nt * 16 + lm) * 72 + ks * 32 + lq * 8);
                acc[nt] = __builtin_amdgcn_mfma_f32_16x16x32_bf16(af, bfr, acc[nt], 0, 0, 0);
            }
        }
        __syncthreads();
    }
#pragma unroll
    for (int nt = 0; nt < 4; ++nt) {
        int col = n0 + nt * 16 + lm;
        float bv = __bfloat162float(bias[col]);
#pragma unroll
        for (int r = 0; r < 4; ++r) {
            int mrow = m0 + 16 * w + lq * 4 + r;
            size_t coff = ((size_t)(mrow >> 8) * strideC + (mrow & 255)) * N;
            float v = acc[nt][r] + bv;
            if constexpr (std::is_same_v<OutT, _Float16>)
                C[coff + col] = (_Float16)v;
            else if constexpr (std::is_same_v<OutT, float>)
                C[coff + col] = v;
            else
                C[coff + col] = __float2bfloat16(v);
        }
    }
}

// ---------- LSTM recurrence chunk: one WG (512 threads) per batch ----------
// Thread j < 256  owns cols j (forget[j])  and j+512 (output[j]); holds c,h state.
// Thread j >= 256 owns cols j (input[j-256]) and j+512 (cell[j-256]).
// Upper half passes {i, ct} via garr; 2 barriers/step.
//
// REGISTER WALL (r1-r7 measured): 512-thr blocks get a hard 128-VGPR budget;
// r7 spilled NOT because residents > 128 but because the fully-unrolled
// 16-deep streamed loop let the scheduler keep ~32 uint4 loads in flight.
// Fix: (a) REGQ=6 (48 weight regs), (b) streamed loop unroll-limited to 2
// with separate accumulators -> worst-case live ~110 regs.
//   q in [0,6)    : LDS (96 KB -> 1 WG/CU)
//   q in [6,12)   : VGPRs (6*2 = 12 uint4 = 48 regs)
//   q in [12,32)  : streamed from per-XCD L2 (320 KB/CU-step)
#define LDSQ 6
#define REGQ 6
#define STRQ 20

__global__ __launch_bounds__(512) void lstm_rec_chunk(
        const _Float16* __restrict__ xg_c,    // [64][TC][1024]
        const uint4* __restrict__ Whq,        // [32][1024] fp16-pair quads
        __hip_bfloat16* __restrict__ hs_c,    // [64][TC][256]
        float* __restrict__ hstate,           // [64][256]
        float* __restrict__ cstate,           // [64][256]
        int first) {
    const int tid = threadIdx.x;   // 0..511
    const int b = blockIdx.x;
    __shared__ uint4 wlds[LDSQ * 1024];           // 96 KB
    __shared__ float garr[512];                   // 2 KB: [0,256)=i, [256,512)=ct
    __shared__ alignas(16) u32 hpair[128];        // h as fp16 pairs, 512 B

    // stage LDS weight quads 0..LDSQ-1 (coalesced)
#pragma unroll
    for (int i = 0; i < LDSQ * 2; ++i)
        wlds[i * 512 + tid] = Whq[i * 512 + tid];

    // register-resident weight quads (statically indexed only)
    uint4 wr0[REGQ], wr1[REGQ];
#pragma unroll
    for (int r = 0; r < REGQ; ++r) {
        wr0[r] = Whq[(LDSQ + r) * 1024 + tid];
        wr1[r] = Whq[(LDSQ + r) * 1024 + tid + 512];
    }
    // streamed quads 12..31: fixed per-step addresses, resident in per-XCD L2
    const uint4* wsa = Whq + (size_t)(LDSQ + REGQ) * 1024 + tid;   // col tid
    const uint4* wsb = wsa + 512;                                   // col tid+512

    float c = 0.f, h = 0.f;
    if (tid < 256) {
        h = first ? 0.f : hstate[b * 256 + tid];
        c = first ? 0.f : cstate[b * 256 + tid];
        float hp = __shfl_xor(h, 1);
        if (!(tid & 1)) {
            hf2 p; p.x = (_Float16)h; p.y = (_Float16)hp;
            hpair[tid >> 1] = __builtin_bit_cast(u32, p);
        }
    }
    __syncthreads();

    const _Float16* xgp = xg_c + (size_t)b * TC * 1024 + tid;
    __hip_bfloat16* hsp = hs_c + (size_t)b * TC * 256 + tid;   // used by tid<256
    const uint4* hq4 = (const uint4*)hpair;

    for (int t = 0; t < TC; ++t) {
        float x0 = (float)xgp[(size_t)t * 1024];
        float x1 = (float)xgp[(size_t)t * 1024 + 512];

        float a0[4] = {0.f, 0.f, 0.f, 0.f};
        float a1[4] = {0.f, 0.f, 0.f, 0.f};

        // LDS-resident quads (q = 0..5)
#pragma unroll
        for (int q = 0; q < LDSQ; ++q) {
            uint4 hv = hq4[q];                     // uniform-address broadcast b128
            uint4 w0 = wlds[q * 1024 + tid];
            uint4 w1 = wlds[q * 1024 + tid + 512];
            a0[q & 3] = dot4(w0, hv, a0[q & 3]);
            a1[q & 3] = dot4(w1, hv, a1[q & 3]);
        }
        // VGPR-resident quads (q = 6..11, static indices only)
#pragma unroll
        for (int r = 0; r < REGQ; ++r) {
            uint4 hv = hq4[LDSQ + r];
            a0[(LDSQ + r) & 3] = dot4(wr0[r], hv, a0[(LDSQ + r) & 3]);
            a1[(LDSQ + r) & 3] = dot4(wr1[r], hv, a1[(LDSQ + r) & 3]);
        }
        // L2-streamed quads (q = 12..31), unroll capped at 2 to bound the
        // number of in-flight loads (the r7 spill cause). Separate stream
        // accumulators avoid runtime indexing into a0/a1.
        float sA0 = 0.f, sA1 = 0.f, sB0 = 0.f, sB1 = 0.f;
#pragma unroll 2
        for (int s = 0; s < STRQ; s += 2) {
            uint4 wa0 = wsa[(size_t)s * 1024];
            uint4 wa1 = wsa[(size_t)(s + 1) * 1024];
            uint4 wb0 = wsb[(size_t)s * 1024];
            uint4 wb1 = wsb[(size_t)(s + 1) * 1024];
            uint4 hva = hq4[LDSQ + REGQ + s];
            uint4 hvb = hq4[LDSQ + REGQ + s + 1];
            sA0 = dot4(wa0, hva, sA0);
            sA1 = dot4(wa1, hvb, sA1);
            sB0 = dot4(wb0, hva, sB0);
            sB1 = dot4(wb1, hvb, sB1);
        }

        float g0 = x0 + (a0[0] + a0[1]) + (a0[2] + a0[3]) + (sA0 + sA1);
        float g1 = x1 + (a1[0] + a1[1]) + (a1[2] + a1[3]) + (sB0 + sB1);

        float s0 = sigf(g0);                                   // f (low) / i (high)
        float s1 = (tid < 256) ? sigf(g1) : tanhf_fast(g1);    // o (low) / ct (high)

        if (tid >= 256) {
            garr[tid - 256] = s0;   // i for h-idx tid-256
            garr[tid]       = s1;   // ct for h-idx tid-256
        }
        __syncthreads();
        if (tid < 256) {
            float ig = garr[tid];
            float ct = garr[tid + 256];
            c = c * s0 + ct * ig;
            h = s1 * tanhf_fast(c);
            hsp[(size_t)t * 256] = __float2bfloat16(h);
            float hp = __shfl_xor(h, 1);
            if (!(tid & 1)) {
                hf2 p; p.x = (_Float16)h; p.y = (_Float16)hp;
                hpair[tid >> 1] = __builtin_bit_cast(u32, p);
            }
        }
        __syncthreads();
    }
    if (tid < 256) {
        hstate[b * 256 + tid] = h;
        cstate[b * 256 + tid] = c;
    }
}

// ---------- launch ----------
extern "C" void kernel_launch(void* const* d_in, const int* in_sizes, int n_in,
                              void* d_out, int out_size, void* d_ws, size_t ws_size,
                              hipStream_t stream) {
    const void* X    = d_in[0];  // [64,2048,128] fp32 (sniffed)
    const void* Wx   = d_in[1];  // [128,1024]
    const void* Wh   = d_in[2];  // [256,1024]
    const void* bg   = d_in[3];  // [1024]
    const void* Wout = d_in[4];  // [256,128]
    const void* bout = d_in[5];  // [128]
    float* out = (float*)d_out;  // [64,2048,128] fp32 (reference output dtype)

    // workspace layout (~47.2 MB)
    char* ws = (char*)d_ws;
    _Float16* xg_c        = (_Float16*)(ws + 0);                 // 33554432
    __hip_bfloat16* Xc_b  = (__hip_bfloat16*)(ws + 33554432);    //  4194304
    __hip_bfloat16* hs_c  = (__hip_bfloat16*)(ws + 37748736);    //  8388608
    uint4* Whq            = (uint4*)(ws + 46137344);             //   524288
    __hip_bfloat16* Wxb   = (__hip_bfloat16*)(ws + 46661632);    //   262144
    __hip_bfloat16* Woutb = (__hip_bfloat16*)(ws + 46923776);    //    65536
    __hip_bfloat16* bgb   = (__hip_bfloat16*)(ws + 46989312);    //     2048
    __hip_bfloat16* boutb = (__hip_bfloat16*)(ws + 46991360);    //      512
    float* hstate         = (float*)(ws + 46991872);             //    65536
    float* cstate         = (float*)(ws + 47057408);             //    65536
    int* flags            = (int*)(ws + 47122944);               //       64

    // 1) per-tensor dtype sniff
    for (int i = 0; i < 6; ++i)
        sniff<<<dim3(1), dim3(256), 0, stream>>>((const u32*)d_in[i],
                                                 in_sizes[i] / 2, flags + i);
    // 2) canonicalize weights/biases to bf16 (and Wh to quad-major fp16 pairs)
    conv_any<<<dim3(512), dim3(256), 0, stream>>>(Wx, Wxb, 131072, flags + 1);
    conv_any<<<dim3(128), dim3(256), 0, stream>>>(Wout, Woutb, 32768, flags + 4);
    conv_any<<<dim3(4),   dim3(256), 0, stream>>>(bg, bgb, 1024, flags + 3);
    conv_any<<<dim3(1),   dim3(256), 0, stream>>>(bout, boutb, 128, flags + 5);
    pack_whq<<<dim3(128), dim3(256), 0, stream>>>(Wh, Whq, flags + 2);

    for (int tc = 0; tc < NCHUNK; ++tc) {
        // 3) X chunk -> bf16 [64][256][128]
        conv_x<<<dim3(8192), dim3(256), 0, stream>>>(X, Xc_b, tc, flags + 0);
        // 4) xg_c = Xc_b @ Wxb + bgb : M=16384, N=1024, K=128
        gemm_bias<_Float16><<<dim3(16, 256), dim3(256), 0, stream>>>(
            Xc_b, Wxb, bgb, xg_c, 1024, 128, 256L, 256L);
        // 5) recurrence over TC steps
        lstm_rec_chunk<<<dim3(64), dim3(512), 0, stream>>>(
            xg_c, Whq, hs_c, hstate, cstate, tc == 0 ? 1 : 0);
        // 6) outc = hs_c @ Woutb + boutb : M=16384, N=128, K=256  (fp32 out)
        float* outc = out + (size_t)tc * TC * 128;
        gemm_bias<float><<<dim3(2, 256), dim3(256), 0, stream>>>(
            hs_c, Woutb, boutb, outc, 128, 256, 256L, 2048L);
    }
}